// Round 1
// baseline (423.328 us; speedup 1.0000x reference)
//
#include <hip/hip_runtime.h>
#include <hip/hip_bf16.h>
#include <stdint.h>

typedef unsigned short ushort_t;
typedef __attribute__((ext_vector_type(8))) short bf16x8;
typedef __attribute__((ext_vector_type(4))) float f32x4;

__device__ __forceinline__ ushort_t f2bf(float f) {
    uint32_t u = __builtin_bit_cast(uint32_t, f);
    u += 0x7FFF + ((u >> 16) & 1);   // RNE
    return (ushort_t)(u >> 16);
}
__device__ __forceinline__ float bf2f(ushort_t h) {
    return __builtin_bit_cast(float, (uint32_t)h << 16);
}

__device__ __forceinline__ f32x4 mfma16(bf16x8 a, bf16x8 b, f32x4 c) {
    return __builtin_amdgcn_mfma_f32_16x16x32_bf16(a, b, c, 0, 0, 0);
}

#define GLL(g, l) __builtin_amdgcn_global_load_lds(                              \
    (const __attribute__((address_space(1))) void*)(g),                          \
    (__attribute__((address_space(3))) void*)(l), 16, 0, 0)

// ---------------- conversion kernels ----------------

__global__ __launch_bounds__(256) void cvt_f32_to_bf16(
    const float* __restrict__ src, ushort_t* __restrict__ dst, int n8)
{
    int i = blockIdx.x * blockDim.x + threadIdx.x;
    if (i >= n8) return;
    const float4* s = (const float4*)src + (size_t)i * 2;
    float4 a = s[0], b = s[1];
    union { bf16x8 v; ushort_t u[8]; } o;
    o.u[0] = f2bf(a.x); o.u[1] = f2bf(a.y); o.u[2] = f2bf(a.z); o.u[3] = f2bf(a.w);
    o.u[4] = f2bf(b.x); o.u[5] = f2bf(b.y); o.u[6] = f2bf(b.z); o.u[7] = f2bf(b.w);
    *(bf16x8*)(dst + (size_t)i * 8) = o.v;
}

__global__ __launch_bounds__(256) void pack_bias(
    const float* __restrict__ bq, const float* __restrict__ bk,
    const float* __restrict__ bv, float* __restrict__ dst)
{
    int i = blockIdx.x * blockDim.x + threadIdx.x;  // 0..3071
    float v = (i < 1024) ? bq[i] : (i < 2048 ? bk[i - 1024] : bv[i - 2048]);
    dst[i] = v;
}

// ---------------- GEMM: C = A (MxK) * B^T (NxK), + bias ----------------
// MODE 0: out = bf16, N=3072 fused QKV -> out base + (n>>10)*M*1024 + m*1024 + (n&1023)
// MODE 1: out = fp32, N=1024, plain [M][1024]

template<int MODE>
__global__ __launch_bounds__(256) void gemm_bt(
    const ushort_t* __restrict__ A, const ushort_t* __restrict__ B,
    const float* __restrict__ bias, void* __restrict__ outp,
    int M, int K)
{
    __shared__ ushort_t As[128 * 32];
    __shared__ ushort_t Bs[128 * 32];
    const int t = threadIdx.x;
    const int wave = t >> 6, lane = t & 63;
    const int m0 = blockIdx.x * 128;
    const int n0 = blockIdx.y * 128;
    const int wr = wave >> 1, wc = wave & 1;
    const int lg = lane >> 4, ln = lane & 15;

    f32x4 acc[4][4];
#pragma unroll
    for (int i = 0; i < 4; ++i)
#pragma unroll
        for (int j = 0; j < 4; ++j) acc[i][j] = (f32x4){0.f, 0.f, 0.f, 0.f};

    for (int k0 = 0; k0 < K; k0 += 32) {
#pragma unroll
        for (int i = 0; i < 2; ++i) {
            int chunk = i * 256 + t;
            int row = chunk >> 2, kc = chunk & 3;
            const ushort_t* ga = A + (size_t)(m0 + row) * K + (k0 + kc * 8);
            GLL(ga, (char*)As + (i * 256 + wave * 64) * 16);
            const ushort_t* gb = B + (size_t)(n0 + row) * K + (k0 + kc * 8);
            GLL(gb, (char*)Bs + (i * 256 + wave * 64) * 16);
        }
        __syncthreads();
        bf16x8 af[4], bfr[4];
#pragma unroll
        for (int mi = 0; mi < 4; ++mi)
            af[mi] = *(const bf16x8*)&As[(wr * 64 + mi * 16 + ln) * 32 + lg * 8];
#pragma unroll
        for (int ni = 0; ni < 4; ++ni)
            bfr[ni] = *(const bf16x8*)&Bs[(wc * 64 + ni * 16 + ln) * 32 + lg * 8];
#pragma unroll
        for (int mi = 0; mi < 4; ++mi)
#pragma unroll
            for (int ni = 0; ni < 4; ++ni)
                acc[mi][ni] = mfma16(af[mi], bfr[ni], acc[mi][ni]);
        __syncthreads();
    }

#pragma unroll
    for (int mi = 0; mi < 4; ++mi) {
#pragma unroll
        for (int ni = 0; ni < 4; ++ni) {
            int n = n0 + wc * 64 + ni * 16 + ln;
            float bval = bias[n];
#pragma unroll
            for (int r = 0; r < 4; ++r) {
                int m = m0 + wr * 64 + mi * 16 + lg * 4 + r;
                float v = acc[mi][ni][r] + bval;
                if (MODE == 0) {
                    int which = n >> 10, col = n & 1023;
                    ushort_t* o = (ushort_t*)outp + (size_t)which * ((size_t)M * 1024)
                                  + (size_t)m * 1024 + col;
                    *o = f2bf(v);
                } else {
                    ((float*)outp)[(size_t)m * 1024 + n] = v;
                }
            }
        }
    }
}

// ---------------- attention helpers ----------------

__device__ __forceinline__ bf16x8 bias8(const float* __restrict__ b, int off) {
    float4 f0 = *(const float4*)(b + off);
    float4 f1 = *(const float4*)(b + off + 4);
    union { bf16x8 v; ushort_t u[8]; } o;
    o.u[0] = f2bf(f0.x); o.u[1] = f2bf(f0.y); o.u[2] = f2bf(f0.z); o.u[3] = f2bf(f0.w);
    o.u[4] = f2bf(f1.x); o.u[5] = f2bf(f1.y); o.u[6] = f2bf(f1.z); o.u[7] = f2bf(f1.w);
    return o.v;
}

// ---------------- local attention: 1 wave per (chunk, head) ----------------
// chunk = 16 consecutive tokens, no padding (16384 % 16 == 0)

__global__ __launch_bounds__(64) void attn_local(
    const ushort_t* __restrict__ Q, const ushort_t* __restrict__ K,
    const ushort_t* __restrict__ V, ushort_t* __restrict__ S)
{
    const int bid = blockIdx.x;
    const int h = bid & 15;
    const int c = bid >> 4;
    const int lane = threadIdx.x;
    const int g = lane >> 4, nn = lane & 15;
    __shared__ ushort_t lds_p[16 * 16];
    __shared__ ushort_t vt[64 * 16];  // vt[d][n] = V[n][d]

    const size_t rowb = (size_t)c * 16;
    size_t aoff = (rowb + nn) * 1024 + h * 64 + g * 8;
    bf16x8 qa0 = *(const bf16x8*)(Q + aoff);
    bf16x8 qa1 = *(const bf16x8*)(Q + aoff + 32);
    bf16x8 kb0 = *(const bf16x8*)(K + aoff);
    bf16x8 kb1 = *(const bf16x8*)(K + aoff + 32);
    f32x4 sc = {0.f, 0.f, 0.f, 0.f};
    sc = mfma16(qa0, kb0, sc);
    sc = mfma16(qa1, kb1, sc);

#pragma unroll
    for (int r = 0; r < 4; ++r) {
        float s = sc[r] * 0.125f;
        float mx = s;
#pragma unroll
        for (int off = 1; off < 16; off <<= 1) mx = fmaxf(mx, __shfl_xor(mx, off, 64));
        float e = __expf(s - mx);
        float sm = e;
#pragma unroll
        for (int off = 1; off < 16; off <<= 1) sm += __shfl_xor(sm, off, 64);
        lds_p[(g * 4 + r) * 16 + nn] = f2bf(e / sm);
    }

#pragma unroll
    for (int it = 0; it < 2; ++it) {
        int u = it * 64 + lane;
        int n = u >> 3, cc = u & 7;
        bf16x8 vv = *(const bf16x8*)(V + (rowb + n) * 1024 + h * 64 + cc * 8);
        union { bf16x8 v; ushort_t u8[8]; } vu; vu.v = vv;
#pragma unroll
        for (int j = 0; j < 8; ++j) vt[(cc * 8 + j) * 16 + n] = vu.u8[j];
    }
    __syncthreads();

    bf16x8 zero8 = {};
    bf16x8 pa = (g < 2) ? *(const bf16x8*)&lds_p[nn * 16 + g * 8] : zero8;
#pragma unroll
    for (int dt = 0; dt < 4; ++dt) {
        bf16x8 vb = (g < 2) ? *(const bf16x8*)&vt[(dt * 16 + nn) * 16 + g * 8] : zero8;
        f32x4 o = mfma16(pa, vb, (f32x4){0.f, 0.f, 0.f, 0.f});
#pragma unroll
        for (int r = 0; r < 4; ++r) {
            size_t orow = rowb + g * 4 + r;
            S[orow * 1024 + h * 64 + dt * 16 + nn] = f2bf(o[r]);
        }
    }
}

// ---------------- atrous attention: 1 wave per (stream, chunk, head) ----------------
// stream s = b*3+dil; dilated token t -> original pos p = 3t+dil; pad if p >= 4096.
// Padded tokens: q/k/v = bias (projection of zero input). Accumulates into S.

__global__ __launch_bounds__(64) void attn_atrous(
    const ushort_t* __restrict__ Q, const ushort_t* __restrict__ K,
    const ushort_t* __restrict__ V,
    const float* __restrict__ bq, const float* __restrict__ bk,
    const float* __restrict__ bv, ushort_t* __restrict__ S)
{
    const int bid = blockIdx.x;
    const int h = bid & 15;
    const int tmp = bid >> 4;
    const int c = tmp % 86;
    const int sidx = tmp / 86;
    const int b = sidx / 3, dil = sidx % 3;
    const int lane = threadIdx.x;
    const int g = lane >> 4, nn = lane & 15;
    __shared__ ushort_t lds_p[16 * 16];
    __shared__ ushort_t vt[64 * 16];

    const int dof = h * 64 + g * 8;
    const int p_n = 3 * (c * 16 + nn) + dil;
    bf16x8 qa0, qa1, kb0, kb1;
    if (p_n < 4096) {
        size_t o = ((size_t)b * 4096 + p_n) * 1024 + dof;
        qa0 = *(const bf16x8*)(Q + o);
        qa1 = *(const bf16x8*)(Q + o + 32);
        kb0 = *(const bf16x8*)(K + o);
        kb1 = *(const bf16x8*)(K + o + 32);
    } else {
        qa0 = bias8(bq, dof); qa1 = bias8(bq, dof + 32);
        kb0 = bias8(bk, dof); kb1 = bias8(bk, dof + 32);
    }
    f32x4 sc = {0.f, 0.f, 0.f, 0.f};
    sc = mfma16(qa0, kb0, sc);
    sc = mfma16(qa1, kb1, sc);

#pragma unroll
    for (int r = 0; r < 4; ++r) {
        float s = sc[r] * 0.125f;
        float mx = s;
#pragma unroll
        for (int off = 1; off < 16; off <<= 1) mx = fmaxf(mx, __shfl_xor(mx, off, 64));
        float e = __expf(s - mx);
        float sm = e;
#pragma unroll
        for (int off = 1; off < 16; off <<= 1) sm += __shfl_xor(sm, off, 64);
        lds_p[(g * 4 + r) * 16 + nn] = f2bf(e / sm);
    }

#pragma unroll
    for (int it = 0; it < 2; ++it) {
        int u = it * 64 + lane;
        int n = u >> 3, cc = u & 7;
        int p_v = 3 * (c * 16 + n) + dil;
        bf16x8 vv = (p_v < 4096)
            ? *(const bf16x8*)(V + ((size_t)b * 4096 + p_v) * 1024 + h * 64 + cc * 8)
            : bias8(bv, h * 64 + cc * 8);
        union { bf16x8 v; ushort_t u8[8]; } vu; vu.v = vv;
#pragma unroll
        for (int j = 0; j < 8; ++j) vt[(cc * 8 + j) * 16 + n] = vu.u8[j];
    }
    __syncthreads();

    bf16x8 zero8 = {};
    bf16x8 pa = (g < 2) ? *(const bf16x8*)&lds_p[nn * 16 + g * 8] : zero8;
#pragma unroll
    for (int dt = 0; dt < 4; ++dt) {
        bf16x8 vb = (g < 2) ? *(const bf16x8*)&vt[(dt * 16 + nn) * 16 + g * 8] : zero8;
        f32x4 o = mfma16(pa, vb, (f32x4){0.f, 0.f, 0.f, 0.f});
#pragma unroll
        for (int r = 0; r < 4; ++r) {
            int p_q = 3 * (c * 16 + g * 4 + r) + dil;
            if (p_q < 4096) {
                size_t off = ((size_t)b * 4096 + p_q) * 1024 + h * 64 + dt * 16 + nn;
                S[off] = f2bf(bf2f(S[off]) + o[r]);
            }
        }
    }
}

// ---------------- launch ----------------

extern "C" void kernel_launch(void* const* d_in, const int* in_sizes, int n_in,
                              void* d_out, int out_size, void* d_ws, size_t ws_size,
                              hipStream_t stream)
{
    const float* x  = (const float*)d_in[0];
    const float* Wq = (const float*)d_in[1];
    const float* bq = (const float*)d_in[2];
    const float* Wk = (const float*)d_in[3];
    const float* bk = (const float*)d_in[4];
    const float* Wv = (const float*)d_in[5];
    const float* bv = (const float*)d_in[6];
    const float* Wo = (const float*)d_in[7];
    const float* bo = (const float*)d_in[8];
    float* out = (float*)d_out;

    const size_t NT = 16384;            // total tokens (4 * 4096)
    ushort_t* xb   = (ushort_t*)d_ws;                  // 16M bf16
    ushort_t* wqkv = xb + NT * 1024;                   // 3M bf16 (Wq|Wk|Wv as B^T rows)
    ushort_t* wo   = wqkv + 3 * 1024 * 1024;           // 1M bf16
    ushort_t* Qb   = wo + 1024 * 1024;                 // 16M bf16
    ushort_t* Kb   = Qb + NT * 1024;
    ushort_t* Vb   = Kb + NT * 1024;
    ushort_t* Sb   = Vb + NT * 1024;                   // local+atrous sum, bf16
    float*    bqkv = (float*)(Sb + NT * 1024);         // 3072 fp32

    // fp32 -> bf16 conversions
    const int n8x = (int)(NT * 1024 / 8);
    cvt_f32_to_bf16<<<n8x / 256, 256, 0, stream>>>(x, xb, n8x);
    const int n8w = 1024 * 1024 / 8;
    cvt_f32_to_bf16<<<n8w / 256, 256, 0, stream>>>(Wq, wqkv,               n8w);
    cvt_f32_to_bf16<<<n8w / 256, 256, 0, stream>>>(Wk, wqkv + 1024 * 1024, n8w);
    cvt_f32_to_bf16<<<n8w / 256, 256, 0, stream>>>(Wv, wqkv + 2 * 1024 * 1024, n8w);
    cvt_f32_to_bf16<<<n8w / 256, 256, 0, stream>>>(Wo, wo, n8w);
    pack_bias<<<12, 256, 0, stream>>>(bq, bk, bv, bqkv);

    // fused QKV projection: (16384x1024) @ (3072x1024)^T
    gemm_bt<0><<<dim3(128, 24), 256, 0, stream>>>(xb, wqkv, bqkv, (void*)Qb, (int)NT, 1024);

    // attention
    attn_local <<<16384, 64, 0, stream>>>(Qb, Kb, Vb, Sb);
    attn_atrous<<<16512, 64, 0, stream>>>(Qb, Kb, Vb, bq, bk, bv, Sb);

    // output projection: (16384x1024) @ (1024x1024)^T -> fp32 out
    gemm_bt<1><<<dim3(128, 8), 256, 0, stream>>>(Sb, wo, bo, (void*)out, (int)NT, 1024);
}

// Round 3
// 368.392 us; speedup vs baseline: 1.1491x; 1.1491x over previous
//
#include <hip/hip_runtime.h>
#include <hip/hip_bf16.h>
#include <stdint.h>

typedef unsigned short ushort_t;
typedef __attribute__((ext_vector_type(8))) short bf16x8;
typedef __attribute__((ext_vector_type(4))) float f32x4;

__device__ __forceinline__ ushort_t f2bf(float f) {
    uint32_t u = __builtin_bit_cast(uint32_t, f);
    u += 0x7FFF + ((u >> 16) & 1);   // RNE
    return (ushort_t)(u >> 16);
}
__device__ __forceinline__ float bf2f(ushort_t h) {
    return __builtin_bit_cast(float, (uint32_t)h << 16);
}

__device__ __forceinline__ f32x4 mfma16(bf16x8 a, bf16x8 b, f32x4 c) {
    return __builtin_amdgcn_mfma_f32_16x16x32_bf16(a, b, c, 0, 0, 0);
}

#define GLL(g, l) __builtin_amdgcn_global_load_lds(                              \
    (const __attribute__((address_space(1))) void*)(g),                          \
    (__attribute__((address_space(3))) void*)(l), 16, 0, 0)

#define CFENCE asm volatile("" ::: "memory")
#define BARRIER do { CFENCE; __builtin_amdgcn_s_barrier(); CFENCE; } while (0)

// ---------------- fused conversion kernel ----------------
// covers: x (f32->bf16), Wq|Wk|Wv|Wo (f32->bf16, packed), bqkv pack (f32)

__device__ __forceinline__ void cvt8(const float* s, ushort_t* d) {
    float4 a = ((const float4*)s)[0], b = ((const float4*)s)[1];
    union { bf16x8 v; ushort_t u[8]; } o;
    o.u[0] = f2bf(a.x); o.u[1] = f2bf(a.y); o.u[2] = f2bf(a.z); o.u[3] = f2bf(a.w);
    o.u[4] = f2bf(b.x); o.u[5] = f2bf(b.y); o.u[6] = f2bf(b.z); o.u[7] = f2bf(b.w);
    *(bf16x8*)d = o.v;
}

__global__ __launch_bounds__(256) void cvt_all(
    const float* __restrict__ x,
    const float* __restrict__ Wq, const float* __restrict__ Wk,
    const float* __restrict__ Wv, const float* __restrict__ Wo,
    const float* __restrict__ bq, const float* __restrict__ bk,
    const float* __restrict__ bv,
    ushort_t* __restrict__ xb, ushort_t* __restrict__ wqkv,
    float* __restrict__ bqkv)
{
    const int NX = 16384 * 1024 / 8;   // 2097152
    const int NW = 1024 * 1024 / 8;    // 131072
    int i = blockIdx.x * 256 + threadIdx.x;
    if (i < NX) {
        cvt8(x + (size_t)i * 8, xb + (size_t)i * 8);
    } else if (i < NX + 4 * NW) {
        int j = i - NX;
        int w = j >> 17, off = j & (NW - 1);
        const float* s = (w == 0) ? Wq : (w == 1) ? Wk : (w == 2) ? Wv : Wo;
        cvt8(s + (size_t)off * 8, wqkv + (size_t)j * 8);   // wqkv then wo, contiguous
    } else if (i < NX + 4 * NW + 384) {
        int j = i - NX - 4 * NW;       // 0..383 (bq|bk|bv, 128 units each)
        int w2 = j >> 7, off = j & 127;
        const float* s = (w2 == 0) ? bq : (w2 == 1) ? bk : bv;
        ((float4*)(bqkv + j * 8))[0] = ((const float4*)(s + off * 8))[0];
        ((float4*)(bqkv + j * 8))[1] = ((const float4*)(s + off * 8))[1];
    }
}

// ---------------- pipelined GEMM: C = A (Mx1024) * B^T (Nx1024) + bias ----
// BM=256, BN=128, BK=64, 8 waves (4m x 2n), 3 LDS buffers, counted vmcnt(6).
// A tile = 512 16B-units (4 STAGE_A calls), B tile = 1024... no: B tile =
// 128 rows * 8 chunks = 1024 units = 2 STAGE_B calls with LOCAL jj in {0,1}.
// MODE 0: bf16 out, N=3072 QKV-split; MODE 1: fp32 out, N=1024.

#define STAGE_A(jj)  { int idx = (jj) * 512 + tid; int row = idx >> 3, ch = idx & 7;    \
    GLL(A + (size_t)(m0 + row) * 1024 + kt2 * 64 + ((ch ^ (row & 7)) * 8),             \
        (char*)Abn + (size_t)idx * 16); }
#define STAGE_B(jj)  { int idx = (jj) * 512 + tid; int row = idx >> 3, ch = idx & 7;    \
    GLL(B + (size_t)(n0 + row) * 1024 + kt2 * 64 + ((ch ^ (row & 7)) * 8),             \
        (char*)Bbn + (size_t)idx * 16); }

template<int MODE>
__global__ __launch_bounds__(512, 2) void gemm3(
    const ushort_t* __restrict__ A, const ushort_t* __restrict__ B,
    const float* __restrict__ bias, void* __restrict__ outp,
    int M, int NTN)
{
    __shared__ ushort_t As[3][256 * 64];   // 96 KiB
    __shared__ ushort_t Bs[3][128 * 64];   // 48 KiB
    const int NK = 16;                     // K = 1024

    const int nwg = gridDim.x;
    const int bid = blockIdx.x;
    const int q8 = nwg >> 3;               // nwg % 8 == 0 for our grids
    const int swz = (bid & 7) * q8 + (bid >> 3);
    const int m0 = (swz / NTN) * 256;
    const int n0 = (swz % NTN) * 128;

    const int tid = threadIdx.x;
    const int wave = tid >> 6, lane = tid & 63;
    const int wm = wave >> 1, wn = wave & 1;
    const int lg = lane >> 4, ln = lane & 15;

    f32x4 acc[4][4];
#pragma unroll
    for (int i = 0; i < 4; ++i)
#pragma unroll
        for (int j = 0; j < 4; ++j) acc[i][j] = (f32x4){0.f, 0.f, 0.f, 0.f};

    // prologue: stage tile 0 -> buf0, tile 1 -> buf1 (6 GLL each)
    {
        ushort_t* Abn = &As[0][0]; ushort_t* Bbn = &Bs[0][0]; int kt2 = 0;
        STAGE_A(0) STAGE_A(1) STAGE_A(2) STAGE_A(3) STAGE_B(0) STAGE_B(1)
    }
    {
        ushort_t* Abn = &As[1][0]; ushort_t* Bbn = &Bs[1][0]; int kt2 = 1;
        STAGE_A(0) STAGE_A(1) STAGE_A(2) STAGE_A(3) STAGE_B(0) STAGE_B(1)
    }
    asm volatile("s_waitcnt vmcnt(6)" ::: "memory");   // tile 0 resident
    BARRIER;

    int bc = 0;
    for (int kt = 0; kt < NK; ++kt) {
        int bn = bc + 2; if (bn >= 3) bn -= 3;
        const ushort_t* Ab = &As[bc][0];
        const ushort_t* Bb = &Bs[bc][0];
        ushort_t* Abn = &As[bn][0];
        ushort_t* Bbn = &Bs[bn][0];
        const int kt2 = kt + 2;
        const bool pf = (kt2 < NK);

        // ---- phase A: ds_read A-frags + B-frags(ni 0,1); stage part 1 ----
        bf16x8 af[4][2], b01[2][2];
#pragma unroll
        for (int mi = 0; mi < 4; ++mi) {
            int row = wm * 64 + mi * 16 + ln;
#pragma unroll
            for (int kk = 0; kk < 2; ++kk)
                af[mi][kk] = *(const bf16x8*)&Ab[row * 64 + (((kk * 4 + lg) ^ (row & 7)) * 8)];
        }
#pragma unroll
        for (int ni = 0; ni < 2; ++ni) {
            int row = wn * 64 + ni * 16 + ln;
#pragma unroll
            for (int kk = 0; kk < 2; ++kk)
                b01[ni][kk] = *(const bf16x8*)&Bb[row * 64 + (((kk * 4 + lg) ^ (row & 7)) * 8)];
        }
        if (pf) { STAGE_A(0) STAGE_A(1) STAGE_A(2) }
        BARRIER;
        __builtin_amdgcn_s_setprio(1);
#pragma unroll
        for (int mi = 0; mi < 4; ++mi)
#pragma unroll
            for (int ni = 0; ni < 2; ++ni) {
                acc[mi][ni] = mfma16(af[mi][0], b01[ni][0], acc[mi][ni]);
                acc[mi][ni] = mfma16(af[mi][1], b01[ni][1], acc[mi][ni]);
            }
        __builtin_amdgcn_s_setprio(0);

        // ---- phase B: ds_read B-frags(ni 2,3); stage part 2 ----
        bf16x8 b23[2][2];
#pragma unroll
        for (int ni = 0; ni < 2; ++ni) {
            int row = wn * 64 + (ni + 2) * 16 + ln;
#pragma unroll
            for (int kk = 0; kk < 2; ++kk)
                b23[ni][kk] = *(const bf16x8*)&Bb[row * 64 + (((kk * 4 + lg) ^ (row & 7)) * 8)];
        }
        if (pf) { STAGE_A(3) STAGE_B(0) STAGE_B(1) }
        BARRIER;
        __builtin_amdgcn_s_setprio(1);
#pragma unroll
        for (int mi = 0; mi < 4; ++mi)
#pragma unroll
            for (int ni = 0; ni < 2; ++ni) {
                acc[mi][ni + 2] = mfma16(af[mi][0], b23[ni][0], acc[mi][ni + 2]);
                acc[mi][ni + 2] = mfma16(af[mi][1], b23[ni][1], acc[mi][ni + 2]);
            }
        __builtin_amdgcn_s_setprio(0);

        // ---- iteration boundary: counted wait, tile kt+1 resident ----
        if (pf) { asm volatile("s_waitcnt vmcnt(6)" ::: "memory"); }
        else    { asm volatile("s_waitcnt vmcnt(0)" ::: "memory"); }
        BARRIER;
        bc += 1; if (bc == 3) bc = 0;
    }

    // ---- epilogue ----
#pragma unroll
    for (int ni = 0; ni < 4; ++ni) {
        int n = n0 + wn * 64 + ni * 16 + ln;
        float bval = bias[n];
#pragma unroll
        for (int mi = 0; mi < 4; ++mi) {
#pragma unroll
            for (int r = 0; r < 4; ++r) {
                int m = m0 + wm * 64 + mi * 16 + lg * 4 + r;
                float v = acc[mi][ni][r] + bval;
                if (MODE == 0) {
                    int which = n >> 10, col = n & 1023;
                    ((ushort_t*)outp)[(size_t)which * ((size_t)M * 1024)
                                      + (size_t)m * 1024 + col] = f2bf(v);
                } else {
                    ((float*)outp)[(size_t)m * 1024 + n] = v;
                }
            }
        }
    }
}

// ---------------- attention helpers ----------------

__device__ __forceinline__ bf16x8 bias8(const float* __restrict__ b, int off) {
    float4 f0 = *(const float4*)(b + off);
    float4 f1 = *(const float4*)(b + off + 4);
    union { bf16x8 v; ushort_t u[8]; } o;
    o.u[0] = f2bf(f0.x); o.u[1] = f2bf(f0.y); o.u[2] = f2bf(f0.z); o.u[3] = f2bf(f0.w);
    o.u[4] = f2bf(f1.x); o.u[5] = f2bf(f1.y); o.u[6] = f2bf(f1.z); o.u[7] = f2bf(f1.w);
    return o.v;
}

// ---------------- local attention: 4 waves/block, 1 wave per (chunk, head) --

__global__ __launch_bounds__(256) void attn_local(
    const ushort_t* __restrict__ Q, const ushort_t* __restrict__ K,
    const ushort_t* __restrict__ V, ushort_t* __restrict__ S)
{
    const int wave = threadIdx.x >> 6, lane = threadIdx.x & 63;
    const int unit = blockIdx.x * 4 + wave;
    const int h = unit & 15;
    const int c = unit >> 4;
    const int g = lane >> 4, nn = lane & 15;
    __shared__ ushort_t lds_p[4][16 * 16];
    __shared__ ushort_t vt[4][64 * 16];  // vt[d][n] = V[n][d]

    const size_t rowb = (size_t)c * 16;
    size_t aoff = (rowb + nn) * 1024 + h * 64 + g * 8;
    bf16x8 qa0 = *(const bf16x8*)(Q + aoff);
    bf16x8 qa1 = *(const bf16x8*)(Q + aoff + 32);
    bf16x8 kb0 = *(const bf16x8*)(K + aoff);
    bf16x8 kb1 = *(const bf16x8*)(K + aoff + 32);
    f32x4 sc = {0.f, 0.f, 0.f, 0.f};
    sc = mfma16(qa0, kb0, sc);
    sc = mfma16(qa1, kb1, sc);

#pragma unroll
    for (int r = 0; r < 4; ++r) {
        float s = sc[r] * 0.125f;
        float mx = s;
#pragma unroll
        for (int off = 1; off < 16; off <<= 1) mx = fmaxf(mx, __shfl_xor(mx, off, 64));
        float e = __expf(s - mx);
        float sm = e;
#pragma unroll
        for (int off = 1; off < 16; off <<= 1) sm += __shfl_xor(sm, off, 64);
        lds_p[wave][(g * 4 + r) * 16 + nn] = f2bf(e / sm);
    }

#pragma unroll
    for (int it = 0; it < 2; ++it) {
        int u = it * 64 + lane;
        int n = u >> 3, cc = u & 7;
        bf16x8 vv = *(const bf16x8*)(V + (rowb + n) * 1024 + h * 64 + cc * 8);
        union { bf16x8 v; ushort_t u8[8]; } vu; vu.v = vv;
#pragma unroll
        for (int j = 0; j < 8; ++j) vt[wave][(cc * 8 + j) * 16 + n] = vu.u8[j];
    }
    __syncthreads();

    bf16x8 zero8 = {};
    bf16x8 pa = (g < 2) ? *(const bf16x8*)&lds_p[wave][nn * 16 + g * 8] : zero8;
#pragma unroll
    for (int dt = 0; dt < 4; ++dt) {
        bf16x8 vb = (g < 2) ? *(const bf16x8*)&vt[wave][(dt * 16 + nn) * 16 + g * 8] : zero8;
        f32x4 o = mfma16(pa, vb, (f32x4){0.f, 0.f, 0.f, 0.f});
#pragma unroll
        for (int r = 0; r < 4; ++r) {
            size_t orow = rowb + g * 4 + r;
            S[orow * 1024 + h * 64 + dt * 16 + nn] = f2bf(o[r]);
        }
    }
}

// ---------------- atrous attention: 4 waves/block ----------------

__global__ __launch_bounds__(256) void attn_atrous(
    const ushort_t* __restrict__ Q, const ushort_t* __restrict__ K,
    const ushort_t* __restrict__ V,
    const float* __restrict__ bq, const float* __restrict__ bk,
    const float* __restrict__ bv, ushort_t* __restrict__ S)
{
    const int wave = threadIdx.x >> 6, lane = threadIdx.x & 63;
    const int unit = blockIdx.x * 4 + wave;
    const int h = unit & 15;
    const int tmp = unit >> 4;
    const int c = tmp % 86;
    const int sidx = tmp / 86;
    const int b = sidx / 3, dil = sidx % 3;
    const int g = lane >> 4, nn = lane & 15;
    __shared__ ushort_t lds_p[4][16 * 16];
    __shared__ ushort_t vt[4][64 * 16];

    const int dof = h * 64 + g * 8;
    const int p_n = 3 * (c * 16 + nn) + dil;
    bf16x8 qa0, qa1, kb0, kb1;
    if (p_n < 4096) {
        size_t o = ((size_t)b * 4096 + p_n) * 1024 + dof;
        qa0 = *(const bf16x8*)(Q + o);
        qa1 = *(const bf16x8*)(Q + o + 32);
        kb0 = *(const bf16x8*)(K + o);
        kb1 = *(const bf16x8*)(K + o + 32);
    } else {
        qa0 = bias8(bq, dof); qa1 = bias8(bq, dof + 32);
        kb0 = bias8(bk, dof); kb1 = bias8(bk, dof + 32);
    }
    f32x4 sc = {0.f, 0.f, 0.f, 0.f};
    sc = mfma16(qa0, kb0, sc);
    sc = mfma16(qa1, kb1, sc);

#pragma unroll
    for (int r = 0; r < 4; ++r) {
        float s = sc[r] * 0.125f;
        float mx = s;
#pragma unroll
        for (int off = 1; off < 16; off <<= 1) mx = fmaxf(mx, __shfl_xor(mx, off, 64));
        float e = __expf(s - mx);
        float sm = e;
#pragma unroll
        for (int off = 1; off < 16; off <<= 1) sm += __shfl_xor(sm, off, 64);
        lds_p[wave][(g * 4 + r) * 16 + nn] = f2bf(e / sm);
    }

#pragma unroll
    for (int it = 0; it < 2; ++it) {
        int u = it * 64 + lane;
        int n = u >> 3, cc = u & 7;
        int p_v = 3 * (c * 16 + n) + dil;
        bf16x8 vv = (p_v < 4096)
            ? *(const bf16x8*)(V + ((size_t)b * 4096 + p_v) * 1024 + h * 64 + cc * 8)
            : bias8(bv, h * 64 + cc * 8);
        union { bf16x8 v; ushort_t u8[8]; } vu; vu.v = vv;
#pragma unroll
        for (int j = 0; j < 8; ++j) vt[wave][(cc * 8 + j) * 16 + n] = vu.u8[j];
    }
    __syncthreads();

    bf16x8 zero8 = {};
    bf16x8 pa = (g < 2) ? *(const bf16x8*)&lds_p[wave][nn * 16 + g * 8] : zero8;
#pragma unroll
    for (int dt = 0; dt < 4; ++dt) {
        bf16x8 vb = (g < 2) ? *(const bf16x8*)&vt[wave][(dt * 16 + nn) * 16 + g * 8] : zero8;
        f32x4 o = mfma16(pa, vb, (f32x4){0.f, 0.f, 0.f, 0.f});
#pragma unroll
        for (int r = 0; r < 4; ++r) {
            int p_q = 3 * (c * 16 + g * 4 + r) + dil;
            if (p_q < 4096) {
                size_t off = ((size_t)b * 4096 + p_q) * 1024 + h * 64 + dt * 16 + nn;
                S[off] = f2bf(bf2f(S[off]) + o[r]);
            }
        }
    }
}

// ---------------- launch ----------------

extern "C" void kernel_launch(void* const* d_in, const int* in_sizes, int n_in,
                              void* d_out, int out_size, void* d_ws, size_t ws_size,
                              hipStream_t stream)
{
    const float* x  = (const float*)d_in[0];
    const float* Wq = (const float*)d_in[1];
    const float* bq = (const float*)d_in[2];
    const float* Wk = (const float*)d_in[3];
    const float* bk = (const float*)d_in[4];
    const float* Wv = (const float*)d_in[5];
    const float* bv = (const float*)d_in[6];
    const float* Wo = (const float*)d_in[7];
    const float* bo = (const float*)d_in[8];
    float* out = (float*)d_out;

    const size_t NT = 16384;            // total tokens (4 * 4096)
    ushort_t* xb   = (ushort_t*)d_ws;                  // 16M bf16
    ushort_t* wqkv = xb + NT * 1024;                   // 3M bf16 (Wq|Wk|Wv rows)
    ushort_t* wo   = wqkv + 3 * 1024 * 1024;           // 1M bf16 (contiguous after wqkv)
    ushort_t* Qb   = wo + 1024 * 1024;                 // 16M bf16
    ushort_t* Kb   = Qb + NT * 1024;
    ushort_t* Vb   = Kb + NT * 1024;
    ushort_t* Sb   = Vb + NT * 1024;                   // local+atrous sum, bf16
    float*    bqkv = (float*)(Sb + NT * 1024);         // 3072 fp32

    // fused fp32 -> bf16 conversion + bias pack
    const int total_units = 2097152 + 4 * 131072 + 384;
    cvt_all<<<(total_units + 255) / 256, 256, 0, stream>>>(
        x, Wq, Wk, Wv, Wo, bq, bk, bv, xb, wqkv, bqkv);

    // fused QKV projection: (16384x1024) @ (3072x1024)^T ; grid 64*24=1536 (%8==0)
    gemm3<0><<<1536, 512, 0, stream>>>(xb, wqkv, bqkv, (void*)Qb, (int)NT, 24);

    // attention
    attn_local <<<4096, 256, 0, stream>>>(Qb, Kb, Vb, Sb);
    attn_atrous<<<4128, 256, 0, stream>>>(Qb, Kb, Vb, bq, bk, bv, Sb);

    // output projection: (16384x1024) @ (1024x1024)^T -> fp32 ; grid 64*8=512
    gemm3<1><<<512, 512, 0, stream>>>(Sb, wo, bo, (void*)out, (int)NT, 8);
}